// Round 1
// baseline (809.959 us; speedup 1.0000x reference)
//
#include <hip/hip_runtime.h>
#include <hip/hip_bf16.h>
#include <math.h>

typedef float f32x4 __attribute__((ext_vector_type(4)));
typedef __bf16 bf16x8 __attribute__((ext_vector_type(8)));

#define NTOK 98
#define NWIN 2048
#define SCALE 0.17677669529663689f

// M rows of the token-major matrices
#define MROWS (NWIN * NTOK)   // 200704

// ---------------- async global->LDS 16B ----------------
__device__ __forceinline__ void g2l16(const void* g, void* l) {
  typedef __attribute__((address_space(1))) const unsigned int GU;
  typedef __attribute__((address_space(3))) unsigned int LU;
  __builtin_amdgcn_global_load_lds((GU*)g, (LU*)l, 16, 0, 0);
}

// ---------------- prep: weights->bf16, bias gather ----------------
__global__ void prep_kernel(const float* __restrict__ qkv_w, const float* __restrict__ proj_w,
                            const float* __restrict__ pbt, const int* __restrict__ rpi,
                            __bf16* __restrict__ qkvw_b, __bf16* __restrict__ projw_b,
                            float* __restrict__ bias) {
  int i = blockIdx.x * blockDim.x + threadIdx.x;
  if (i < 768 * 256) qkvw_b[i] = (__bf16)qkv_w[i];
  int j = i - 768 * 256;
  if (j >= 0 && j < 256 * 256) projw_b[j] = (__bf16)proj_w[j];
  int t = i - (768 * 256 + 256 * 256);
  if (t >= 0 && t < 8 * NTOK * NTOK) {
    int h = t / (NTOK * NTOK);
    int ij = t - h * (NTOK * NTOK);
    bias[t] = pbt[rpi[ij] * 8 + h];
  }
}

// ---------------- QKV GEMM: C[M][768] = x[M][256] @ W[768][256]^T ----------------
__launch_bounds__(256)
__global__ void gemm_qkv(const float* __restrict__ A, const __bf16* __restrict__ W,
                         __bf16* __restrict__ C) {
  __shared__ __align__(16) __bf16 As[128 * 64];
  __shared__ __align__(16) __bf16 Bs[128 * 64];
  const int bid = blockIdx.x;
  const int m0 = (bid / 6) * 128;
  const int n0 = (bid % 6) * 128;
  const int tid = threadIdx.x;
  const int lane = tid & 63;
  const int wid = tid >> 6;
  const int wm = wid & 1, wn = wid >> 1;
  const int lr = lane & 15;
  const int lg = lane >> 4;
  f32x4 acc[4][4] = {};

  for (int k0 = 0; k0 < 256; k0 += 64) {
    // stage A: fp32 -> bf16 through regs
#pragma unroll
    for (int c = 0; c < 4; ++c) {
      int flat8 = tid + c * 256;            // 0..1023 chunks of 8 elems
      int row = flat8 >> 3, c8 = flat8 & 7;
      const float* ap = A + (size_t)(m0 + row) * 256 + k0 + c8 * 8;
      float4 f0 = *(const float4*)ap;
      float4 f1 = *(const float4*)(ap + 4);
      bf16x8 hv;
      hv[0] = (__bf16)f0.x; hv[1] = (__bf16)f0.y; hv[2] = (__bf16)f0.z; hv[3] = (__bf16)f0.w;
      hv[4] = (__bf16)f1.x; hv[5] = (__bf16)f1.y; hv[6] = (__bf16)f1.z; hv[7] = (__bf16)f1.w;
      *(bf16x8*)(&As[row * 64 + c8 * 8]) = hv;
    }
    // stage B: async direct-to-LDS (bf16 weights)
#pragma unroll
    for (int it = 0; it < 4; ++it) {
      int c = wid * 4 + it;                 // wave-uniform chunk
      int flat16 = c * 64 + lane;           // 16B unit index
      int row = flat16 >> 3, c16 = flat16 & 7;
      g2l16(W + (size_t)(n0 + row) * 256 + k0 + c16 * 8, (void*)(Bs + c * 512));
    }
    __syncthreads();
#pragma unroll
    for (int kk = 0; kk < 2; ++kk) {
      bf16x8 a[4], b[4];
#pragma unroll
      for (int m = 0; m < 4; ++m)
        a[m] = *(const bf16x8*)&As[(wm * 64 + m * 16 + lr) * 64 + kk * 32 + lg * 8];
#pragma unroll
      for (int n = 0; n < 4; ++n)
        b[n] = *(const bf16x8*)&Bs[(wn * 64 + n * 16 + lr) * 64 + kk * 32 + lg * 8];
#pragma unroll
      for (int m = 0; m < 4; ++m)
#pragma unroll
        for (int n = 0; n < 4; ++n)
          acc[m][n] = __builtin_amdgcn_mfma_f32_16x16x32_bf16(a[m], b[n], acc[m][n], 0, 0, 0);
    }
    __syncthreads();
  }
#pragma unroll
  for (int m = 0; m < 4; ++m) {
    int row = m0 + wm * 64 + m * 16 + lg * 4;
#pragma unroll
    for (int n = 0; n < 4; ++n) {
      int col = n0 + wn * 64 + n * 16 + lr;
#pragma unroll
      for (int r = 0; r < 4; ++r)
        C[(size_t)(row + r) * 768 + col] = (__bf16)acc[m][n][r];
    }
  }
}

// ---------------- attention: one block per (window, head) ----------------
__launch_bounds__(256)
__global__ void attn_kernel(const __bf16* __restrict__ qkv, const float* __restrict__ mask,
                            const float* __restrict__ bias, __bf16* __restrict__ y) {
  __shared__ __align__(16) __bf16 Qs[112 * 32];
  __shared__ __align__(16) __bf16 Ks[112 * 32];
  __shared__ __align__(16) __bf16 VT[32 * 128];
  __shared__ __align__(16) __bf16 Ps[112 * 128];
  const int bx = blockIdx.x;
  const int w = bx >> 3, h = bx & 7;
  const int tid = threadIdx.x;
  const int lane = tid & 63, wid = tid >> 6;
  const int lr = lane & 15, lg = lane >> 4;
  const size_t tokbase = (size_t)w * NTOK * 768;

  for (int idx = tid; idx < 112 * 32; idx += 256) {
    int i = idx >> 5, d = idx & 31;
    __bf16 qv = (__bf16)0.f, kv = (__bf16)0.f;
    if (i < NTOK) {
      qv = qkv[tokbase + (size_t)i * 768 + h * 32 + d];
      kv = qkv[tokbase + (size_t)i * 768 + 256 + h * 32 + d];
    }
    Qs[idx] = qv;
    Ks[idx] = kv;
  }
  for (int idx = tid; idx < 32 * 128; idx += 256) {
    int d = idx >> 7, j = idx & 127;
    __bf16 vv = (__bf16)0.f;
    if (j < NTOK) vv = qkv[tokbase + (size_t)j * 768 + 512 + h * 32 + d];
    VT[idx] = vv;
  }
  for (int idx = tid; idx < 112 * 16; idx += 256) {  // zero never-written P cols 112..127
    int i = idx >> 4, j = 112 + (idx & 15);
    Ps[i * 128 + j] = (__bf16)0.f;
  }
  __syncthreads();

  const float* maskp = mask + (size_t)(w & 255) * (NTOK * NTOK);
  const float* biasp = bias + (size_t)h * (NTOK * NTOK);
  const f32x4 fzero = {0.f, 0.f, 0.f, 0.f};

  float rinv[2][4];
#pragma unroll
  for (int t = 0; t < 2; ++t) {
    int it = wid + t * 4;
    if (it < 7) {
      int i0 = it * 16;
      bf16x8 aq = *(const bf16x8*)&Qs[(i0 + lr) * 32 + lg * 8];
      f32x4 s[7];
#pragma unroll
      for (int jt = 0; jt < 7; ++jt) {
        bf16x8 bk = *(const bf16x8*)&Ks[(jt * 16 + lr) * 32 + lg * 8];
        s[jt] = __builtin_amdgcn_mfma_f32_16x16x32_bf16(aq, bk, fzero, 0, 0, 0);
      }
#pragma unroll
      for (int r = 0; r < 4; ++r) {
        int i = i0 + lg * 4 + r;
        int ic = i < NTOK ? i : NTOK - 1;   // clamp pad rows (values unused)
        float mx = -INFINITY;
        float sv[7];
#pragma unroll
        for (int jt = 0; jt < 7; ++jt) {
          int j = jt * 16 + lr;
          float xv;
          if (j < NTOK)
            xv = SCALE * s[jt][r] + biasp[ic * NTOK + j] + maskp[ic * NTOK + j];
          else
            xv = -INFINITY;
          sv[jt] = xv;
          mx = fmaxf(mx, xv);
        }
#pragma unroll
        for (int off = 1; off < 16; off <<= 1) mx = fmaxf(mx, __shfl_xor(mx, off));
        float sum = 0.f;
#pragma unroll
        for (int jt = 0; jt < 7; ++jt) {
          float p = __expf(sv[jt] - mx);
          sv[jt] = p;
          sum += p;
        }
#pragma unroll
        for (int off = 1; off < 16; off <<= 1) sum += __shfl_xor(sum, off);
        rinv[t][r] = 1.f / sum;
        int irow = i0 + lg * 4 + r;
#pragma unroll
        for (int jt = 0; jt < 7; ++jt)
          Ps[irow * 128 + jt * 16 + lr] = (__bf16)sv[jt];
      }
    }
  }
  __syncthreads();

  // PV: out[i][d] = sum_j P[i][j] * V[j][d], K padded to 128
#pragma unroll
  for (int t = 0; t < 2; ++t) {
    int it = wid + t * 4;
    if (it < 7) {
      int i0 = it * 16;
#pragma unroll
      for (int dt = 0; dt < 2; ++dt) {
        f32x4 o = {0.f, 0.f, 0.f, 0.f};
#pragma unroll
        for (int ks = 0; ks < 4; ++ks) {
          bf16x8 pa = *(const bf16x8*)&Ps[(i0 + lr) * 128 + ks * 32 + lg * 8];
          bf16x8 vb = *(const bf16x8*)&VT[(dt * 16 + lr) * 128 + ks * 32 + lg * 8];
          o = __builtin_amdgcn_mfma_f32_16x16x32_bf16(pa, vb, o, 0, 0, 0);
        }
#pragma unroll
        for (int r = 0; r < 4; ++r) {
          int i = i0 + lg * 4 + r;
          if (i < NTOK)
            y[((size_t)w * NTOK + i) * 256 + h * 32 + dt * 16 + lr] = (__bf16)(o[r] * rinv[t][r]);
        }
      }
    }
  }
}

// ---------------- proj GEMM: out[M][256] = y[M][256] @ W[256][256]^T + b ----------------
__launch_bounds__(256)
__global__ void gemm_proj(const __bf16* __restrict__ A, const __bf16* __restrict__ W,
                          const float* __restrict__ pb, float* __restrict__ C) {
  __shared__ __align__(16) __bf16 As[128 * 64];
  __shared__ __align__(16) __bf16 Bs[128 * 64];
  const int bid = blockIdx.x;
  const int m0 = (bid / 2) * 128;
  const int n0 = (bid % 2) * 128;
  const int tid = threadIdx.x;
  const int lane = tid & 63;
  const int wid = tid >> 6;
  const int wm = wid & 1, wn = wid >> 1;
  const int lr = lane & 15;
  const int lg = lane >> 4;
  f32x4 acc[4][4] = {};

  for (int k0 = 0; k0 < 256; k0 += 64) {
#pragma unroll
    for (int it = 0; it < 4; ++it) {
      int c = wid * 4 + it;
      int flat16 = c * 64 + lane;
      int row = flat16 >> 3, c16 = flat16 & 7;
      g2l16(A + (size_t)(m0 + row) * 256 + k0 + c16 * 8, (void*)(As + c * 512));
      g2l16(W + (size_t)(n0 + row) * 256 + k0 + c16 * 8, (void*)(Bs + c * 512));
    }
    __syncthreads();
#pragma unroll
    for (int kk = 0; kk < 2; ++kk) {
      bf16x8 a[4], b[4];
#pragma unroll
      for (int m = 0; m < 4; ++m)
        a[m] = *(const bf16x8*)&As[(wm * 64 + m * 16 + lr) * 64 + kk * 32 + lg * 8];
#pragma unroll
      for (int n = 0; n < 4; ++n)
        b[n] = *(const bf16x8*)&Bs[(wn * 64 + n * 16 + lr) * 64 + kk * 32 + lg * 8];
#pragma unroll
      for (int m = 0; m < 4; ++m)
#pragma unroll
        for (int n = 0; n < 4; ++n)
          acc[m][n] = __builtin_amdgcn_mfma_f32_16x16x32_bf16(a[m], b[n], acc[m][n], 0, 0, 0);
    }
    __syncthreads();
  }
#pragma unroll
  for (int m = 0; m < 4; ++m) {
    int row = m0 + wm * 64 + m * 16 + lg * 4;
#pragma unroll
    for (int n = 0; n < 4; ++n) {
      int col = n0 + wn * 64 + n * 16 + lr;
      float bv = pb[col];
#pragma unroll
      for (int r = 0; r < 4; ++r)
        C[(size_t)(row + r) * 256 + col] = acc[m][n][r] + bv;
    }
  }
}

// ---------------- launch ----------------
extern "C" void kernel_launch(void* const* d_in, const int* in_sizes, int n_in,
                              void* d_out, int out_size, void* d_ws, size_t ws_size,
                              hipStream_t stream) {
  const float* x      = (const float*)d_in[0];
  const float* mask   = (const float*)d_in[1];
  const float* pbt    = (const float*)d_in[2];
  const float* qkv_w  = (const float*)d_in[3];
  const float* proj_w = (const float*)d_in[4];
  const float* proj_b = (const float*)d_in[5];
  const int*   rpi    = (const int*)d_in[6];
  float* out = (float*)d_out;

  char* ws = (char*)d_ws;
  __bf16* qkv     = (__bf16*)(ws);                    // 200704*768*2 = 308,281,344
  __bf16* y       = (__bf16*)(ws + 308281344);        // 200704*256*2 = 102,760,448
  __bf16* qkvw_b  = (__bf16*)(ws + 411041792);        // 393,216
  __bf16* projw_b = (__bf16*)(ws + 411435008);        // 131,072
  float*  bias    = (float*) (ws + 411566080);        // 307,328  (total ~411.9 MB)

  int prep_n = 768 * 256 + 256 * 256 + 8 * NTOK * NTOK;
  prep_kernel<<<(prep_n + 255) / 256, 256, 0, stream>>>(qkv_w, proj_w, pbt, rpi,
                                                        qkvw_b, projw_b, bias);
  gemm_qkv<<<(MROWS / 128) * 6, 256, 0, stream>>>(x, qkvw_b, qkv);
  attn_kernel<<<NWIN * 8, 256, 0, stream>>>(qkv, mask, bias, y);
  gemm_proj<<<(MROWS / 128) * 2, 256, 0, stream>>>(y, projw_b, proj_b, out);
}

// Round 2
// 805.156 us; speedup vs baseline: 1.0060x; 1.0060x over previous
//
#include <hip/hip_runtime.h>
#include <hip/hip_bf16.h>
#include <math.h>

typedef float f32x4 __attribute__((ext_vector_type(4)));
typedef __bf16 bf16x8 __attribute__((ext_vector_type(8)));

#define NTOK 98
#define NWIN 2048
#define NN (NTOK * NTOK)            // 9604
#define SCALE 0.17677669529663689f

// ---------------- prep: weights->bf16, combined bias+mask ----------------
// cmb[wm][h][i][j] = pbt[rpi[i*98+j]*8 + h] + mask[wm][i][j]
__global__ void prep_kernel(const float* __restrict__ qkv_w, const float* __restrict__ proj_w,
                            const float* __restrict__ pbt, const int* __restrict__ rpi,
                            const float* __restrict__ mask,
                            __bf16* __restrict__ qkvw_b, __bf16* __restrict__ projw_b,
                            float* __restrict__ cmb) {
  int i = blockIdx.x * 256 + threadIdx.x;
  if (i < 768 * 256) qkvw_b[i] = (__bf16)qkv_w[i];
  if (i < 256 * 256) projw_b[i] = (__bf16)proj_w[i];
  if (i < 256 * 8 * NN) {
    int wmh = i / NN;                 // wm*8 + h
    int ij = i - wmh * NN;
    int wm = wmh >> 3, h = wmh & 7;
    cmb[i] = pbt[rpi[ij] * 8 + h] + mask[wm * NN + ij];
  }
}

// ---------------- fused per-window kernel ----------------
// 512 threads = 8 waves. LDS 128KB:
//   Xs [128][256] bf16 swz8   @0      (65536)
//   Qs [128][32]  bf16 swz4   @65536  (8192)
//   Ks [128][32]  bf16 swz4   @73728  (8192)
//   VT [32][128]  bf16 swz8   @81920  (8192)
//   P  [128][128] bf16 swz8   @90112  (32768)
//   Yp [128][32]  bf16 swz4   @122880 (8192)   total 131072
__launch_bounds__(512, 2)
__global__ void fused_kernel(const float* __restrict__ x, const float* __restrict__ cmb,
                             const __bf16* __restrict__ Wqkv, const __bf16* __restrict__ Wproj,
                             const float* __restrict__ pb, float* __restrict__ out) {
  __shared__ char smem[131072];
  char* XsB = smem;
  char* QsB = smem + 65536;
  char* KsB = smem + 73728;
  char* VTB = smem + 81920;
  char* PB  = smem + 90112;
  char* YpB = smem + 122880;

  const int win = blockIdx.x;
  const int tid = threadIdx.x;
  const int lane = tid & 63, wv = tid >> 6;
  const int lr = lane & 15, lg = lane >> 4;
  const int wm2 = wv >> 1, wn2 = wv & 1;   // QKV GEMM: 4M x 2N
  const int wm = wv >> 2, wn = wv & 3;     // proj:     2M x 4N
  const f32x4 fz = {0.f, 0.f, 0.f, 0.f};

  // ---- stage x -> Xs (fp32 -> bf16, swizzled); rows 98..127 zero
  const float* xw = x + (size_t)win * NTOK * 256;
  for (int c = tid; c < 128 * 32; c += 512) {   // 16B chunks: 32 per row
    int row = c >> 5, slot = c & 31;
    bf16x8 hv;
#pragma unroll
    for (int e = 0; e < 8; ++e) hv[e] = (__bf16)0.f;
    if (row < NTOK) {
      const float* p = xw + row * 256 + slot * 8;
      float4 f0 = *(const float4*)p;
      float4 f1 = *(const float4*)(p + 4);
      hv[0] = (__bf16)f0.x; hv[1] = (__bf16)f0.y; hv[2] = (__bf16)f0.z; hv[3] = (__bf16)f0.w;
      hv[4] = (__bf16)f1.x; hv[5] = (__bf16)f1.y; hv[6] = (__bf16)f1.z; hv[7] = (__bf16)f1.w;
    }
    *(bf16x8*)(XsB + row * 512 + ((slot * 16) ^ ((row & 7) << 4))) = hv;
  }
  // zero P cols 112..127 once (softmax only rewrites cols 0..111)
  for (int c = tid; c < 128 * 2; c += 512) {
    int row = c >> 1, s = c & 1;
    bf16x8 hv;
#pragma unroll
    for (int e = 0; e < 8; ++e) hv[e] = (__bf16)0.f;
    *(bf16x8*)(PB + row * 256 + ((224 + s * 16) ^ ((row & 7) << 4))) = hv;
  }
  __syncthreads();

  f32x4 oacc[4][4] = {};    // persistent proj accumulator (rows wm*64.., cols wn*64..)

  for (int h = 0; h < 8; ++h) {
    // ---- QKV partial GEMM: N=96 cols {q32,k32,v32} of head h, K=256
    f32x4 acc2[2][3] = {};
    const int c0base = wn2 * 48;
#pragma unroll
    for (int kk = 0; kk < 8; ++kk) {
      bf16x8 a[2], b[3];
#pragma unroll
      for (int m = 0; m < 2; ++m) {
        int row = wm2 * 32 + m * 16 + lr;
        a[m] = *(const bf16x8*)(XsB + row * 512 + ((kk * 64 + lg * 16) ^ ((row & 7) << 4)));
      }
#pragma unroll
      for (int n = 0; n < 3; ++n) {
        int c0 = c0base + n * 16;
        int sec = c0 >> 5;
        int d = (c0 & 31) + lr;
        int grow = sec * 256 + h * 32 + d;
        b[n] = *(const bf16x8*)(Wqkv + (size_t)grow * 256 + kk * 32 + lg * 8);
      }
#pragma unroll
      for (int m = 0; m < 2; ++m)
#pragma unroll
        for (int n = 0; n < 3; ++n)
          acc2[m][n] = __builtin_amdgcn_mfma_f32_16x16x32_bf16(a[m], b[n], acc2[m][n], 0, 0, 0);
    }
    // scatter C to Qs/Ks/VT (swizzled)
#pragma unroll
    for (int m = 0; m < 2; ++m)
#pragma unroll
      for (int n = 0; n < 3; ++n) {
        int c0 = c0base + n * 16;
        int sec = c0 >> 5;
        int d = (c0 & 31) + lr;
#pragma unroll
        for (int r = 0; r < 4; ++r) {
          int row = wm2 * 32 + m * 16 + lg * 4 + r;
          __bf16 v = (__bf16)acc2[m][n][r];
          if (sec == 0)      *(__bf16*)(QsB + row * 64 + ((2 * d) ^ ((row & 3) << 4))) = v;
          else if (sec == 1) *(__bf16*)(KsB + row * 64 + ((2 * d) ^ ((row & 3) << 4))) = v;
          else               *(__bf16*)(VTB + d * 256 + ((2 * row) ^ ((d & 7) << 4))) = v;
        }
      }
    __syncthreads();

    // ---- S = Q K^T, i-tile = wv (16 rows per wave)
    const int i0 = wv * 16;
    const int arow = i0 + lr;
    bf16x8 aq = *(const bf16x8*)(QsB + arow * 64 + ((lg * 16) ^ ((arow & 3) << 4)));
    f32x4 s[7];
#pragma unroll
    for (int jt = 0; jt < 7; ++jt) {
      int brow = jt * 16 + lr;
      bf16x8 bk = *(const bf16x8*)(KsB + brow * 64 + ((lg * 16) ^ ((brow & 3) << 4)));
      s[jt] = __builtin_amdgcn_mfma_f32_16x16x32_bf16(aq, bk, fz, 0, 0, 0);
    }

    // ---- softmax (wave-parallel over 16-lane groups), write P bf16
    const float* cw = cmb + (size_t)(((win & 255) * 8 + h)) * NN;
    float rinv[4];
#pragma unroll
    for (int r = 0; r < 4; ++r) {
      int i = i0 + lg * 4 + r;
      int ic = i < NTOK ? i : NTOK - 1;
      const float* cr = cw + ic * NTOK;
      float sv[7];
      float mx = -INFINITY;
#pragma unroll
      for (int jt = 0; jt < 7; ++jt) {
        int j = jt * 16 + lr;
        float xv = (j < NTOK) ? fmaf(SCALE, s[jt][r], cr[j]) : -INFINITY;
        sv[jt] = xv;
        mx = fmaxf(mx, xv);
      }
#pragma unroll
      for (int off = 1; off < 16; off <<= 1) mx = fmaxf(mx, __shfl_xor(mx, off));
      float sum = 0.f;
#pragma unroll
      for (int jt = 0; jt < 7; ++jt) { float p = __expf(sv[jt] - mx); sv[jt] = p; sum += p; }
#pragma unroll
      for (int off = 1; off < 16; off <<= 1) sum += __shfl_xor(sum, off);
      rinv[r] = 1.f / sum;
#pragma unroll
      for (int jt = 0; jt < 7; ++jt)
        *(__bf16*)(PB + i * 256 + ((2 * (jt * 16 + lr)) ^ ((i & 7) << 4))) = (__bf16)sv[jt];
    }

    // ---- PV: out[i][d] = sum_j P[i][j] * VT[d][j]  (K padded to 128, same-wave rows)
#pragma unroll
    for (int dt = 0; dt < 2; ++dt) {
      f32x4 o = fz;
#pragma unroll
      for (int ks = 0; ks < 4; ++ks) {
        int prow = i0 + lr;
        bf16x8 pa = *(const bf16x8*)(PB + prow * 256 + ((ks * 64 + lg * 16) ^ ((prow & 7) << 4)));
        int vrow = dt * 16 + lr;
        bf16x8 vb = *(const bf16x8*)(VTB + vrow * 256 + ((ks * 64 + lg * 16) ^ ((vrow & 7) << 4)));
        o = __builtin_amdgcn_mfma_f32_16x16x32_bf16(pa, vb, o, 0, 0, 0);
      }
#pragma unroll
      for (int r = 0; r < 4; ++r) {
        int row = i0 + lg * 4 + r;
        int col = dt * 16 + lr;
        *(__bf16*)(YpB + row * 64 + ((2 * col) ^ ((row & 3) << 4))) = (__bf16)(o[r] * rinv[r]);
      }
    }
    __syncthreads();

    // ---- proj partial: oacc += Yp[128][32] @ Wproj[:, h*32..+32]^T
    bf16x8 pa2[4], pbv[4];
#pragma unroll
    for (int m = 0; m < 4; ++m) {
      int row = wm * 64 + m * 16 + lr;
      pa2[m] = *(const bf16x8*)(YpB + row * 64 + ((lg * 16) ^ ((row & 3) << 4)));
    }
#pragma unroll
    for (int n = 0; n < 4; ++n) {
      int grow = wn * 64 + n * 16 + lr;
      pbv[n] = *(const bf16x8*)(Wproj + (size_t)grow * 256 + h * 32 + lg * 8);
    }
#pragma unroll
    for (int m = 0; m < 4; ++m)
#pragma unroll
      for (int n = 0; n < 4; ++n)
        oacc[m][n] = __builtin_amdgcn_mfma_f32_16x16x32_bf16(pa2[m], pbv[n], oacc[m][n], 0, 0, 0);
    // no barrier needed: next head's Yp writes are gated by the next post-QKV barrier
  }

  // ---- epilogue: out = oacc + proj_b, rows < 98 only
  float* ow = out + (size_t)win * NTOK * 256;
#pragma unroll
  for (int m = 0; m < 4; ++m) {
    int row0 = wm * 64 + m * 16 + lg * 4;
    if (row0 >= NTOK) continue;           // all 4 rows out of range
#pragma unroll
    for (int n = 0; n < 4; ++n) {
      int col = wn * 64 + n * 16 + lr;
      float bv = pb[col];
#pragma unroll
      for (int r = 0; r < 4; ++r) {
        int row = row0 + r;
        if (row < NTOK) ow[(size_t)row * 256 + col] = oacc[m][n][r] + bv;
      }
    }
  }
}

// ---------------- launch ----------------
extern "C" void kernel_launch(void* const* d_in, const int* in_sizes, int n_in,
                              void* d_out, int out_size, void* d_ws, size_t ws_size,
                              hipStream_t stream) {
  const float* x      = (const float*)d_in[0];
  const float* mask   = (const float*)d_in[1];
  const float* pbt    = (const float*)d_in[2];
  const float* qkv_w  = (const float*)d_in[3];
  const float* proj_w = (const float*)d_in[4];
  const float* proj_b = (const float*)d_in[5];
  const int*   rpi    = (const int*)d_in[6];
  float* out = (float*)d_out;

  char* ws = (char*)d_ws;
  __bf16* qkvw_b  = (__bf16*)(ws);                  // 768*256*2   = 393216
  __bf16* projw_b = (__bf16*)(ws + 393216);         // 256*256*2   = 131072
  float*  cmb     = (float*) (ws + 524288);         // 256*8*9604*4 = 78,675,968

  int prep_n = 256 * 8 * NN;                        // covers weight conversions too
  prep_kernel<<<(prep_n + 255) / 256, 256, 0, stream>>>(qkv_w, proj_w, pbt, rpi, mask,
                                                        qkvw_b, projw_b, cmb);
  fused_kernel<<<NWIN, 512, 0, stream>>>(x, cmb, qkvw_b, projw_b, proj_b, out);
}